// Round 1
// baseline (869.208 us; speedup 1.0000x reference)
//
#include <hip/hip_runtime.h>
#include <hip/hip_bf16.h>
#include <math.h>

#define DM   1024
#define DFF  4096
#define NHEAD 16
#define DKH  64
#define SEQ  2048
#define NBATCH 4
#define NTOK 8192          // NBATCH*SEQ
#define QKV_LD 3072        // q|k|v concatenated per token

typedef __attribute__((ext_vector_type(8))) __bf16 bf16x8;
typedef __attribute__((ext_vector_type(8))) short short8;
typedef __attribute__((ext_vector_type(4))) float f32x4;
typedef __attribute__((ext_vector_type(4))) unsigned short ushort4v;

__device__ __forceinline__ unsigned short f2bf(float f) {
    unsigned u = __builtin_bit_cast(unsigned, f);
    u += 0x7fffu + ((u >> 16) & 1u);   // round-to-nearest-even
    return (unsigned short)(u >> 16);
}

__device__ __forceinline__ void gload_lds16(const void* g, void* l) {
    __builtin_amdgcn_global_load_lds(
        (const __attribute__((address_space(1))) unsigned int*)g,
        (__attribute__((address_space(3))) unsigned int*)l, 16, 0, 0);
}

// ---------------- weight transpose + fp32->bf16 : dst[C][R] = src[R][C] ----------------
__global__ __launch_bounds__(256) void transpose_cvt(
        const float* __restrict__ src, unsigned short* __restrict__ dst, int R, int C) {
    __shared__ unsigned short tile[32][33];
    const int c0 = blockIdx.x * 32, r0 = blockIdx.y * 32;
    const int tx = threadIdx.x & 31, ty = threadIdx.x >> 5;   // ty 0..7
    #pragma unroll
    for (int j = 0; j < 32; j += 8)
        tile[ty + j][tx] = f2bf(src[(size_t)(r0 + ty + j) * C + (c0 + tx)]);
    __syncthreads();
    #pragma unroll
    for (int j = 0; j < 32; j += 8)
        dst[(size_t)(c0 + ty + j) * R + (r0 + tx)] = tile[tx][ty + j];
}

// ---------------- bias concat (bq|bk|bv) ----------------
__global__ __launch_bounds__(256) void concat_bias(
        const float* __restrict__ a, const float* __restrict__ b,
        const float* __restrict__ c, float* __restrict__ out) {
    int i = blockIdx.x * 256 + threadIdx.x;            // 0..3071
    out[i] = (i < 1024) ? a[i] : (i < 2048 ? b[i - 1024] : c[i - 2048]);
}

// ---------------- layernorm fp32 -> bf16 (one row per block) ----------------
__global__ __launch_bounds__(256) void ln_kernel(
        const float* __restrict__ x, const float* __restrict__ g,
        const float* __restrict__ b, unsigned short* __restrict__ out) {
    const int row = blockIdx.x, t = threadIdx.x;
    const float4 v = ((const float4*)(x + (size_t)row * DM))[t];
    float s1 = v.x + v.y + v.z + v.w;
    float s2 = v.x * v.x + v.y * v.y + v.z * v.z + v.w * v.w;
    #pragma unroll
    for (int off = 32; off > 0; off >>= 1) {
        s1 += __shfl_xor(s1, off, 64);
        s2 += __shfl_xor(s2, off, 64);
    }
    __shared__ float w1[4], w2[4];
    const int wid = t >> 6, lane = t & 63;
    if (lane == 0) { w1[wid] = s1; w2[wid] = s2; }
    __syncthreads();
    s1 = w1[0] + w1[1] + w1[2] + w1[3];
    s2 = w2[0] + w2[1] + w2[2] + w2[3];
    const float mu = s1 * (1.0f / DM);
    const float rs = rsqrtf(s2 * (1.0f / DM) - mu * mu + 1e-5f);
    const float4 gv = ((const float4*)g)[t];
    const float4 bv = ((const float4*)b)[t];
    ushort4v o;
    o[0] = f2bf((v.x - mu) * rs * gv.x + bv.x);
    o[1] = f2bf((v.y - mu) * rs * gv.y + bv.y);
    o[2] = f2bf((v.z - mu) * rs * gv.z + bv.z);
    o[3] = f2bf((v.w - mu) * rs * gv.w + bv.w);
    *(ushort4v*)(out + (size_t)row * DM + t * 4) = o;
}

// ---------------- bf16 GEMM: C[M,N] = A[M,K] * BT[N,K]^T + bias (+res) ----------------
// EP: 0 bias->bf16 | 1 bias+res->f32 | 2 bias+GELU->bf16 | 3 bias+res->f32
template<int EP>
__global__ __launch_bounds__(256) void gemm_bf16(
        const unsigned short* __restrict__ A, const unsigned short* __restrict__ BT,
        const float* __restrict__ bias, const float* __restrict__ res,
        void* __restrict__ outp, int M, int N, int K) {
    const int lane = threadIdx.x & 63;
    const int wid  = threadIdx.x >> 6;
    const int m0 = blockIdx.y * 128;
    const int n0 = blockIdx.x * 128;
    __shared__ short As[128 * 32];
    __shared__ short Bs[128 * 32];
    f32x4 acc[4][4] = {};
    const int wm = wid >> 1, wn = wid & 1;
    const int srow = lane >> 2;          // 0..15
    const int scol = (lane & 3) << 3;    // 0,8,16,24

    for (int k0 = 0; k0 < K; k0 += 32) {
        __syncthreads();
        #pragma unroll
        for (int i = 0; i < 2; ++i) {
            const int rt = (wid * 2 + i) * 16;
            gload_lds16(A  + (size_t)(m0 + rt + srow) * K + k0 + scol, &As[(wid * 2 + i) * 512]);
            gload_lds16(BT + (size_t)(n0 + rt + srow) * K + k0 + scol, &Bs[(wid * 2 + i) * 512]);
        }
        __syncthreads();
        bf16x8 af[4], bfr[4];
        #pragma unroll
        for (int mi = 0; mi < 4; ++mi)
            af[mi] = *(const bf16x8*)&As[(wm * 64 + mi * 16 + (lane & 15)) * 32 + ((lane >> 4) << 3)];
        #pragma unroll
        for (int ni = 0; ni < 4; ++ni)
            bfr[ni] = *(const bf16x8*)&Bs[(wn * 64 + ni * 16 + (lane & 15)) * 32 + ((lane >> 4) << 3)];
        #pragma unroll
        for (int mi = 0; mi < 4; ++mi)
            #pragma unroll
            for (int ni = 0; ni < 4; ++ni)
                acc[mi][ni] = __builtin_amdgcn_mfma_f32_16x16x32_bf16(af[mi], bfr[ni], acc[mi][ni], 0, 0, 0);
    }

    const int r_base = m0 + wm * 64 + ((lane >> 4) << 2);
    const int c_base = n0 + wn * 64 + (lane & 15);
    #pragma unroll
    for (int ni = 0; ni < 4; ++ni) {
        const int col = c_base + ni * 16;
        const float bv = bias[col];
        #pragma unroll
        for (int mi = 0; mi < 4; ++mi) {
            #pragma unroll
            for (int i = 0; i < 4; ++i) {
                const int row = r_base + mi * 16 + i;
                const size_t idx = (size_t)row * N + col;
                float v = acc[mi][ni][i] + bv;
                if (EP == 1 || EP == 3) v += res[idx];
                if (EP == 2) v = 0.5f * v * (1.0f + erff(v * 0.70710678118f));
                if (EP == 0 || EP == 2) ((unsigned short*)outp)[idx] = f2bf(v);
                else                    ((float*)outp)[idx] = v;
            }
        }
    }
}

// ---------------- flash attention (non-causal), bf16 in/out ----------------
// qkv: [NTOK][3072] = q|k|v per token; o: [NTOK][1024]
__global__ __launch_bounds__(256) void attn_kernel(
        const unsigned short* __restrict__ qkv, unsigned short* __restrict__ o) {
    const int lane = threadIdx.x & 63;
    const int wid  = threadIdx.x >> 6;
    const int bh = blockIdx.y;
    const int b = bh >> 4, h = bh & 15;
    const int tb = b * SEQ;
    const int q0 = blockIdx.x * 64 + wid * 16;   // this wave's 16 q rows

    const unsigned short* qp = qkv;
    const unsigned short* kp = qkv + 1024;
    const unsigned short* vp = qkv + 2048;

    __shared__ short VT[64 * 40];       // V^T tile: [d=64][kcol stride 40]
    __shared__ short P[4][16 * 40];     // per-wave P: [qrow=16][kcol stride 40]

    // Q fragments (held for whole loop)
    bf16x8 qf0, qf1;
    {
        const int r = q0 + (lane & 15);
        const int d = (lane >> 4) << 3;
        const unsigned short* qrow = qp + (size_t)(tb + r) * QKV_LD + h * 64 + d;
        qf0 = *(const bf16x8*)qrow;
        qf1 = *(const bf16x8*)(qrow + 32);
    }

    float m_r[4], l_r[4];
    f32x4 oacc[4];
    #pragma unroll
    for (int i = 0; i < 4; ++i) { m_r[i] = -1e30f; l_r[i] = 0.0f; }
    #pragma unroll
    for (int n = 0; n < 4; ++n) oacc[n] = f32x4{0.f, 0.f, 0.f, 0.f};

    for (int kv0 = 0; kv0 < SEQ; kv0 += 32) {
        __syncthreads();   // prior PV reads of VT done
        // stage V^T (all 256 threads; 32 rows x 64 cols)
        {
            const int rv = threadIdx.x >> 3;          // 0..31 (k row)
            const int c0 = (threadIdx.x & 7) * 8;     // d col
            const short8 vv = *(const short8*)(vp + (size_t)(tb + kv0 + rv) * QKV_LD + h * 64 + c0);
            #pragma unroll
            for (int j = 0; j < 8; ++j)
                VT[(c0 + j) * 40 + rv] = vv[j];
        }
        // QK^T for 32 key cols (2 col blocks x 2 k-steps)
        f32x4 s0 = {0.f, 0.f, 0.f, 0.f}, s1 = {0.f, 0.f, 0.f, 0.f};
        {
            const int d = (lane >> 4) << 3;
            const unsigned short* kr0 = kp + (size_t)(tb + kv0 + (lane & 15)) * QKV_LD + h * 64 + d;
            const unsigned short* kr1 = kr0 + (size_t)16 * QKV_LD;
            bf16x8 ka = *(const bf16x8*)kr0;
            bf16x8 kb = *(const bf16x8*)(kr0 + 32);
            s0 = __builtin_amdgcn_mfma_f32_16x16x32_bf16(qf0, ka, s0, 0, 0, 0);
            s0 = __builtin_amdgcn_mfma_f32_16x16x32_bf16(qf1, kb, s0, 0, 0, 0);
            ka = *(const bf16x8*)kr1;
            kb = *(const bf16x8*)(kr1 + 32);
            s1 = __builtin_amdgcn_mfma_f32_16x16x32_bf16(qf0, ka, s1, 0, 0, 0);
            s1 = __builtin_amdgcn_mfma_f32_16x16x32_bf16(qf1, kb, s1, 0, 0, 0);
        }
        // online softmax (rows = (lane>>4)*4+i, cols = lane&15 and 16+(lane&15))
        float p0[4], p1[4];
        #pragma unroll
        for (int i = 0; i < 4; ++i) {
            const float a = s0[i] * 0.125f;
            const float c = s1[i] * 0.125f;
            float tm = fmaxf(a, c);
            #pragma unroll
            for (int off = 1; off < 16; off <<= 1)
                tm = fmaxf(tm, __shfl_xor(tm, off, 64));
            const float newm = fmaxf(m_r[i], tm);
            const float es = __expf(m_r[i] - newm);
            p0[i] = __expf(a - newm);
            p1[i] = __expf(c - newm);
            float rs = p0[i] + p1[i];
            #pragma unroll
            for (int off = 1; off < 16; off <<= 1)
                rs += __shfl_xor(rs, off, 64);
            l_r[i] = l_r[i] * es + rs;
            m_r[i] = newm;
            #pragma unroll
            for (int n = 0; n < 4; ++n) oacc[n][i] *= es;
        }
        // write P (bf16) to per-wave LDS
        #pragma unroll
        for (int i = 0; i < 4; ++i) {
            const int pr = ((lane >> 4) * 4 + i) * 40;
            P[wid][pr + (lane & 15)]      = (short)f2bf(p0[i]);
            P[wid][pr + 16 + (lane & 15)] = (short)f2bf(p1[i]);
        }
        __syncthreads();   // VT writes visible
        // PV
        const bf16x8 pf = *(const bf16x8*)&P[wid][(lane & 15) * 40 + ((lane >> 4) << 3)];
        #pragma unroll
        for (int n = 0; n < 4; ++n) {
            const bf16x8 vf = *(const bf16x8*)&VT[(n * 16 + (lane & 15)) * 40 + ((lane >> 4) << 3)];
            oacc[n] = __builtin_amdgcn_mfma_f32_16x16x32_bf16(pf, vf, oacc[n], 0, 0, 0);
        }
    }
    // normalize + store
    float inv[4];
    #pragma unroll
    for (int i = 0; i < 4; ++i) inv[i] = 1.0f / l_r[i];
    #pragma unroll
    for (int n = 0; n < 4; ++n) {
        #pragma unroll
        for (int i = 0; i < 4; ++i) {
            const int row = (lane >> 4) * 4 + i;
            o[(size_t)(tb + q0 + row) * DM + h * 64 + n * 16 + (lane & 15)] = f2bf(oacc[n][i] * inv[i]);
        }
    }
}

extern "C" void kernel_launch(void* const* d_in, const int* in_sizes, int n_in,
                              void* d_out, int out_size, void* d_ws, size_t ws_size,
                              hipStream_t stream) {
    const float* x    = (const float*)d_in[0];
    const float* Wq   = (const float*)d_in[1];
    const float* bq   = (const float*)d_in[2];
    const float* Wk   = (const float*)d_in[3];
    const float* bk   = (const float*)d_in[4];
    const float* Wv   = (const float*)d_in[5];
    const float* bv   = (const float*)d_in[6];
    const float* Wo   = (const float*)d_in[7];
    const float* bo   = (const float*)d_in[8];
    const float* ln1g = (const float*)d_in[9];
    const float* ln1b = (const float*)d_in[10];
    const float* ln2g = (const float*)d_in[11];
    const float* ln2b = (const float*)d_in[12];
    const float* W1   = (const float*)d_in[13];
    const float* b1   = (const float*)d_in[14];
    const float* W2   = (const float*)d_in[15];
    const float* b2   = (const float*)d_in[16];

    char* ws = (char*)d_ws;
    size_t off = 0;
    auto alloc = [&](size_t bytes) {
        char* p = ws + off;
        off = (off + bytes + 255) & ~(size_t)255;
        return p;
    };
    unsigned short* wqkvT = (unsigned short*)alloc((size_t)3072 * 1024 * 2);
    unsigned short* woT   = (unsigned short*)alloc((size_t)1024 * 1024 * 2);
    unsigned short* w1T   = (unsigned short*)alloc((size_t)4096 * 1024 * 2);
    unsigned short* w2T   = (unsigned short*)alloc((size_t)1024 * 4096 * 2);
    float*          bqkv  = (float*)alloc((size_t)3072 * 4);
    unsigned short* hbuf  = (unsigned short*)alloc((size_t)NTOK * DM * 2);
    unsigned short* qkv   = (unsigned short*)alloc((size_t)NTOK * 3072 * 2);
    unsigned short* obuf  = (unsigned short*)alloc((size_t)NTOK * DM * 2);
    float*          x2    = (float*)alloc((size_t)NTOK * DM * 4);
    unsigned short* h2    = (unsigned short*)alloc((size_t)NTOK * DM * 2);
    unsigned short* gbuf  = (unsigned short*)alloc((size_t)NTOK * DFF * 2);

    // 1) weight transposes (fp32 -> bf16, [N][K])
    transpose_cvt<<<dim3(32, 32), 256, 0, stream>>>(Wq, wqkvT,                 1024, 1024);
    transpose_cvt<<<dim3(32, 32), 256, 0, stream>>>(Wk, wqkvT + 1024 * 1024,   1024, 1024);
    transpose_cvt<<<dim3(32, 32), 256, 0, stream>>>(Wv, wqkvT + 2 * 1024 * 1024, 1024, 1024);
    transpose_cvt<<<dim3(32, 32), 256, 0, stream>>>(Wo, woT,                   1024, 1024);
    transpose_cvt<<<dim3(128, 32), 256, 0, stream>>>(W1, w1T, 1024, 4096);
    transpose_cvt<<<dim3(32, 128), 256, 0, stream>>>(W2, w2T, 4096, 1024);
    concat_bias<<<12, 256, 0, stream>>>(bq, bk, bv, bqkv);

    // 2) LN1
    ln_kernel<<<NTOK, 256, 0, stream>>>(x, ln1g, ln1b, hbuf);

    // 3) QKV projection (fused): [8192,3072]
    gemm_bf16<0><<<dim3(3072 / 128, NTOK / 128), 256, 0, stream>>>(
        hbuf, wqkvT, bqkv, nullptr, qkv, NTOK, 3072, 1024);

    // 4) attention
    attn_kernel<<<dim3(SEQ / 64, NBATCH * NHEAD), 256, 0, stream>>>(qkv, obuf);

    // 5) Wo projection + residual -> x2 (f32)
    gemm_bf16<1><<<dim3(1024 / 128, NTOK / 128), 256, 0, stream>>>(
        obuf, woT, bo, x, x2, NTOK, 1024, 1024);

    // 6) LN2
    ln_kernel<<<NTOK, 256, 0, stream>>>(x2, ln2g, ln2b, h2);

    // 7) W1 + exact GELU
    gemm_bf16<2><<<dim3(4096 / 128, NTOK / 128), 256, 0, stream>>>(
        h2, w1T, b1, nullptr, gbuf, NTOK, 4096, 1024);

    // 8) W2 + residual -> out (f32)
    gemm_bf16<3><<<dim3(1024 / 128, NTOK / 128), 256, 0, stream>>>(
        gbuf, w2T, b2, x2, d_out, NTOK, 1024, 4096);

    (void)in_sizes; (void)n_in; (void)out_size; (void)ws_size;
}

// Round 3
// 792.103 us; speedup vs baseline: 1.0973x; 1.0973x over previous
//
#include <hip/hip_runtime.h>
#include <hip/hip_bf16.h>
#include <math.h>

#define DM   1024
#define DFF  4096
#define NHEAD 16
#define DKH  64
#define SEQ  2048
#define NBATCH 4
#define NTOK 8192          // NBATCH*SEQ
#define QKV_LD 3072        // q|k|v concatenated per token

typedef __attribute__((ext_vector_type(8))) __bf16 bf16x8;
typedef __attribute__((ext_vector_type(8))) short short8;
typedef __attribute__((ext_vector_type(4))) float f32x4;
typedef __attribute__((ext_vector_type(16))) float f32x16;
typedef __attribute__((ext_vector_type(4))) unsigned int u32x4;
typedef __attribute__((ext_vector_type(4))) unsigned short ushort4v;

__device__ __forceinline__ unsigned short f2bf(float f) {
    unsigned u = __builtin_bit_cast(unsigned, f);
    u += 0x7fffu + ((u >> 16) & 1u);   // round-to-nearest-even
    return (unsigned short)(u >> 16);
}

__device__ __forceinline__ void gload_lds16(const void* g, void* l) {
    __builtin_amdgcn_global_load_lds(
        (const __attribute__((address_space(1))) unsigned int*)g,
        (__attribute__((address_space(3))) unsigned int*)l, 16, 0, 0);
}

// ---------------- weight transpose + fp32->bf16 : dst[C][R] = src[R][C] ----------------
__global__ __launch_bounds__(256) void transpose_cvt(
        const float* __restrict__ src, unsigned short* __restrict__ dst, int R, int C) {
    __shared__ unsigned short tile[32][33];
    const int c0 = blockIdx.x * 32, r0 = blockIdx.y * 32;
    const int tx = threadIdx.x & 31, ty = threadIdx.x >> 5;   // ty 0..7
    #pragma unroll
    for (int j = 0; j < 32; j += 8)
        tile[ty + j][tx] = f2bf(src[(size_t)(r0 + ty + j) * C + (c0 + tx)]);
    __syncthreads();
    #pragma unroll
    for (int j = 0; j < 32; j += 8)
        dst[(size_t)(c0 + ty + j) * R + (r0 + tx)] = tile[tx][ty + j];
}

// ---------------- bias concat (bq|bk|bv) ----------------
__global__ __launch_bounds__(256) void concat_bias(
        const float* __restrict__ a, const float* __restrict__ b,
        const float* __restrict__ c, float* __restrict__ out) {
    int i = blockIdx.x * 256 + threadIdx.x;            // 0..3071
    out[i] = (i < 1024) ? a[i] : (i < 2048 ? b[i - 1024] : c[i - 2048]);
}

// ---------------- layernorm fp32 -> bf16 (one row per block) ----------------
__global__ __launch_bounds__(256) void ln_kernel(
        const float* __restrict__ x, const float* __restrict__ g,
        const float* __restrict__ b, unsigned short* __restrict__ out) {
    const int row = blockIdx.x, t = threadIdx.x;
    const float4 v = ((const float4*)(x + (size_t)row * DM))[t];
    float s1 = v.x + v.y + v.z + v.w;
    float s2 = v.x * v.x + v.y * v.y + v.z * v.z + v.w * v.w;
    #pragma unroll
    for (int off = 32; off > 0; off >>= 1) {
        s1 += __shfl_xor(s1, off, 64);
        s2 += __shfl_xor(s2, off, 64);
    }
    __shared__ float w1[4], w2[4];
    const int wid = t >> 6, lane = t & 63;
    if (lane == 0) { w1[wid] = s1; w2[wid] = s2; }
    __syncthreads();
    s1 = w1[0] + w1[1] + w1[2] + w1[3];
    s2 = w2[0] + w2[1] + w2[2] + w2[3];
    const float mu = s1 * (1.0f / DM);
    const float rs = rsqrtf(s2 * (1.0f / DM) - mu * mu + 1e-5f);
    const float4 gv = ((const float4*)g)[t];
    const float4 bv = ((const float4*)b)[t];
    ushort4v o;
    o[0] = f2bf((v.x - mu) * rs * gv.x + bv.x);
    o[1] = f2bf((v.y - mu) * rs * gv.y + bv.y);
    o[2] = f2bf((v.z - mu) * rs * gv.z + bv.z);
    o[3] = f2bf((v.w - mu) * rs * gv.w + bv.w);
    *(ushort4v*)(out + (size_t)row * DM + t * 4) = o;
}

// ---------------- bf16 GEMM: C[M,N] = A[M,K] * BT[N,K]^T + bias (+res) ----------------
// EP: 0 bias->bf16 | 1 bias+res->f32 | 2 bias+GELU->bf16 | 3 bias+res->f32
template<int EP>
__global__ __launch_bounds__(256) void gemm_bf16(
        const unsigned short* __restrict__ A, const unsigned short* __restrict__ BT,
        const float* __restrict__ bias, const float* __restrict__ res,
        void* __restrict__ outp, int M, int N, int K) {
    const int lane = threadIdx.x & 63;
    const int wid  = threadIdx.x >> 6;
    const int m0 = blockIdx.y * 128;
    const int n0 = blockIdx.x * 128;
    __shared__ short As[128 * 32];
    __shared__ short Bs[128 * 32];
    f32x4 acc[4][4] = {};
    const int wm = wid >> 1, wn = wid & 1;
    const int srow = lane >> 2;          // 0..15
    const int scol = (lane & 3) << 3;    // 0,8,16,24

    for (int k0 = 0; k0 < K; k0 += 32) {
        __syncthreads();
        #pragma unroll
        for (int i = 0; i < 2; ++i) {
            const int rt = (wid * 2 + i) * 16;
            gload_lds16(A  + (size_t)(m0 + rt + srow) * K + k0 + scol, &As[(wid * 2 + i) * 512]);
            gload_lds16(BT + (size_t)(n0 + rt + srow) * K + k0 + scol, &Bs[(wid * 2 + i) * 512]);
        }
        __syncthreads();
        bf16x8 af[4], bfr[4];
        #pragma unroll
        for (int mi = 0; mi < 4; ++mi)
            af[mi] = *(const bf16x8*)&As[(wm * 64 + mi * 16 + (lane & 15)) * 32 + ((lane >> 4) << 3)];
        #pragma unroll
        for (int ni = 0; ni < 4; ++ni)
            bfr[ni] = *(const bf16x8*)&Bs[(wn * 64 + ni * 16 + (lane & 15)) * 32 + ((lane >> 4) << 3)];
        #pragma unroll
        for (int mi = 0; mi < 4; ++mi)
            #pragma unroll
            for (int ni = 0; ni < 4; ++ni)
                acc[mi][ni] = __builtin_amdgcn_mfma_f32_16x16x32_bf16(af[mi], bfr[ni], acc[mi][ni], 0, 0, 0);
    }

    const int r_base = m0 + wm * 64 + ((lane >> 4) << 2);
    const int c_base = n0 + wn * 64 + (lane & 15);
    #pragma unroll
    for (int ni = 0; ni < 4; ++ni) {
        const int col = c_base + ni * 16;
        const float bv = bias[col];
        #pragma unroll
        for (int mi = 0; mi < 4; ++mi) {
            #pragma unroll
            for (int i = 0; i < 4; ++i) {
                const int row = r_base + mi * 16 + i;
                const size_t idx = (size_t)row * N + col;
                float v = acc[mi][ni][i] + bv;
                if (EP == 1 || EP == 3) v += res[idx];
                if (EP == 2) v = 0.5f * v * (1.0f + erff(v * 0.70710678118f));
                if (EP == 0 || EP == 2) ((unsigned short*)outp)[idx] = f2bf(v);
                else                    ((float*)outp)[idx] = v;
            }
        }
    }
}

// ---------------- V transpose: vT[bh][d][s] from qkv V-part ----------------
__global__ __launch_bounds__(256) void vtr_kernel(
        const unsigned short* __restrict__ qkv, unsigned short* __restrict__ vT) {
    __shared__ unsigned short tile[64][72];   // 64 tok x 64 d (pad: 144B rows, 16B aligned)
    const int bh = blockIdx.y, t0 = blockIdx.x * 64;
    const int b = bh >> 4, h = bh & 15;
    const int tx = threadIdx.x & 7, ty = threadIdx.x >> 3;    // ty 0..31
    #pragma unroll
    for (int j = 0; j < 64; j += 32) {
        short8 v = *(const short8*)(qkv + (size_t)(b * SEQ + t0 + ty + j) * QKV_LD + 2048 + h * 64 + tx * 8);
        *(short8*)&tile[ty + j][tx * 8] = v;
    }
    __syncthreads();
    #pragma unroll
    for (int j = 0; j < 64; j += 32) {
        const int d = ty + j;
        short8 ov;
        #pragma unroll
        for (int e = 0; e < 8; ++e) ov[e] = tile[tx * 8 + e][d];
        *(short8*)(vT + ((size_t)bh * 64 + d) * SEQ + t0 + tx * 8) = ov;
    }
}

// ---------------- flash attention, swapped-QK^T 32x32 structure ----------------
// qkv: [NTOK][3072]; vT: [64][64][2048]; o: [NTOK][1024]
__global__ __launch_bounds__(256) void attn_kernel(
        const unsigned short* __restrict__ qkv, const unsigned short* __restrict__ vT,
        unsigned short* __restrict__ o) {
    const int lane = threadIdx.x & 63;
    const int wid  = threadIdx.x >> 6;
    const int l31  = lane & 31;
    const int hi   = lane >> 5;
    const int bh = blockIdx.y;
    const int b = bh >> 4, h = bh & 15;
    const int tb = b * SEQ;
    const int q0 = blockIdx.x * 128 + wid * 32;   // this wave's 32 q rows

    const unsigned short* qp = qkv + (size_t)(tb + q0 + l31) * QKV_LD + h * 64 + hi * 8;
    const unsigned short* kp = qkv + 1024 + (size_t)tb * QKV_LD + h * 64 + hi * 8;
    const unsigned short* vp = vT + ((size_t)bh * 64 + l31) * SEQ + hi * 8;

    // Q fragments: B-operand, col=q=l31, k=d-slice
    bf16x8 qf[4];
    #pragma unroll
    for (int s = 0; s < 4; ++s) qf[s] = *(const bf16x8*)(qp + 16 * s);

    f32x16 oacc0 = {}, oacc1 = {};
    float m_r = -1e30f, l_r = 0.0f;
    const float CE = 0.18033688011f;   // (1/8) * log2(e)

    for (int kv0 = 0; kv0 < SEQ; kv0 += 32) {
        // QK^T: S^T[kv][q] = K * Q^T  (A = K rows, B = Q^T)
        const unsigned short* kr = kp + (size_t)(kv0 + l31) * QKV_LD;
        f32x16 S = {};
        #pragma unroll
        for (int s = 0; s < 4; ++s) {
            const bf16x8 kf = *(const bf16x8*)(kr + 16 * s);
            S = __builtin_amdgcn_mfma_f32_32x32x16_bf16(kf, qf[s], S, 0, 0, 0);
        }
        // V^T fragments (issue early; B-operand for PV)
        bf16x8 vf[2][2];
        #pragma unroll
        for (int s = 0; s < 2; ++s)
            #pragma unroll
            for (int n = 0; n < 2; ++n)
                vf[s][n] = *(const bf16x8*)(vp + (size_t)n * 32 * SEQ + kv0 + 16 * s);

        // online softmax: lane holds 16 kv-rows for one q (col = l31)
        float tm = S[0];
        #pragma unroll
        for (int r = 1; r < 16; ++r) tm = fmaxf(tm, S[r]);
        tm = fmaxf(tm, __shfl_xor(tm, 32, 64));
        if (!__all(tm - m_r <= 44.0f)) {        // defer-max (T13): exp2 arg stays < 8
            const float mn = fmaxf(m_r, tm);
            const float es = exp2f((m_r - mn) * CE);
            l_r *= es;
            #pragma unroll
            for (int r = 0; r < 16; ++r) { oacc0[r] *= es; oacc1[r] *= es; }
            m_r = mn;
        }
        float p[16];
        float rs = 0.0f;
        #pragma unroll
        for (int r = 0; r < 16; ++r) {
            p[r] = exp2f((S[r] - m_r) * CE);
            rs += p[r];
        }
        rs += __shfl_xor(rs, 32, 64);
        l_r += rs;

        // P -> bf16 A-fragments via cvt_pk + permlane32_swap (T12)
        unsigned pk[8];
        #pragma unroll
        for (int i = 0; i < 8; ++i) {
            unsigned rr;
            asm("v_cvt_pk_bf16_f32 %0, %1, %2" : "=v"(rr) : "v"(p[2 * i]), "v"(p[2 * i + 1]));
            pk[i] = rr;
        }
        asm volatile("v_permlane32_swap_b32 %0, %1" : "+v"(pk[0]), "+v"(pk[2]));
        asm volatile("v_permlane32_swap_b32 %0, %1" : "+v"(pk[1]), "+v"(pk[3]));
        asm volatile("v_permlane32_swap_b32 %0, %1" : "+v"(pk[4]), "+v"(pk[6]));
        asm volatile("v_permlane32_swap_b32 %0, %1" : "+v"(pk[5]), "+v"(pk[7]));
        const bf16x8 A0 = __builtin_bit_cast(bf16x8, (u32x4){pk[0], pk[1], pk[2], pk[3]});
        const bf16x8 A1 = __builtin_bit_cast(bf16x8, (u32x4){pk[4], pk[5], pk[6], pk[7]});

        oacc0 = __builtin_amdgcn_mfma_f32_32x32x16_bf16(A0, vf[0][0], oacc0, 0, 0, 0);
        oacc1 = __builtin_amdgcn_mfma_f32_32x32x16_bf16(A0, vf[0][1], oacc1, 0, 0, 0);
        oacc0 = __builtin_amdgcn_mfma_f32_32x32x16_bf16(A1, vf[1][0], oacc0, 0, 0, 0);
        oacc1 = __builtin_amdgcn_mfma_f32_32x32x16_bf16(A1, vf[1][1], oacc1, 0, 0, 0);
    }

    // redistribute 1/l across lanes (O rows != S^T cols) via tiny per-wave LDS
    __shared__ float lsum[4][32];
    if (lane < 32) lsum[wid][l31] = 1.0f / l_r;
    // same-wave LDS dependency: in-order DS + compiler lgkmcnt, no barrier needed
    float inv[16];
    #pragma unroll
    for (int r = 0; r < 16; ++r)
        inv[r] = lsum[wid][(r & 3) + 8 * (r >> 2) + 4 * hi];

    unsigned short* op = o + (size_t)(tb + q0) * DM + h * 64 + l31;
    #pragma unroll
    for (int r = 0; r < 16; ++r) {
        const int q = (r & 3) + 8 * (r >> 2) + 4 * hi;
        op[(size_t)q * DM]      = f2bf(oacc0[r] * inv[r]);
        op[(size_t)q * DM + 32] = f2bf(oacc1[r] * inv[r]);
    }
}

extern "C" void kernel_launch(void* const* d_in, const int* in_sizes, int n_in,
                              void* d_out, int out_size, void* d_ws, size_t ws_size,
                              hipStream_t stream) {
    const float* x    = (const float*)d_in[0];
    const float* Wq   = (const float*)d_in[1];
    const float* bq   = (const float*)d_in[2];
    const float* Wk   = (const float*)d_in[3];
    const float* bk   = (const float*)d_in[4];
    const float* Wv   = (const float*)d_in[5];
    const float* bv   = (const float*)d_in[6];
    const float* Wo   = (const float*)d_in[7];
    const float* bo   = (const float*)d_in[8];
    const float* ln1g = (const float*)d_in[9];
    const float* ln1b = (const float*)d_in[10];
    const float* ln2g = (const float*)d_in[11];
    const float* ln2b = (const float*)d_in[12];
    const float* W1   = (const float*)d_in[13];
    const float* b1   = (const float*)d_in[14];
    const float* W2   = (const float*)d_in[15];
    const float* b2   = (const float*)d_in[16];

    char* ws = (char*)d_ws;
    size_t off = 0;
    auto alloc = [&](size_t bytes) {
        char* p = ws + off;
        off = (off + bytes + 255) & ~(size_t)255;
        return p;
    };
    unsigned short* wqkvT = (unsigned short*)alloc((size_t)3072 * 1024 * 2);
    unsigned short* woT   = (unsigned short*)alloc((size_t)1024 * 1024 * 2);
    unsigned short* w1T   = (unsigned short*)alloc((size_t)4096 * 1024 * 2);
    unsigned short* w2T   = (unsigned short*)alloc((size_t)1024 * 4096 * 2);
    float*          bqkv  = (float*)alloc((size_t)3072 * 4);
    unsigned short* hbuf  = (unsigned short*)alloc((size_t)NTOK * DM * 2);
    unsigned short* qkv   = (unsigned short*)alloc((size_t)NTOK * 3072 * 2);
    unsigned short* obuf  = (unsigned short*)alloc((size_t)NTOK * DM * 2);
    float*          x2    = (float*)alloc((size_t)NTOK * DM * 4);
    unsigned short* h2    = (unsigned short*)alloc((size_t)NTOK * DM * 2);
    unsigned short* gbuf  = (unsigned short*)alloc((size_t)NTOK * DFF * 2);
    // vT aliases gbuf: vT live only in steps 4a-4b, gbuf first written in step 7
    unsigned short* vTbuf = gbuf;

    // 1) weight transposes (fp32 -> bf16, [N][K])
    transpose_cvt<<<dim3(32, 32), 256, 0, stream>>>(Wq, wqkvT,                 1024, 1024);
    transpose_cvt<<<dim3(32, 32), 256, 0, stream>>>(Wk, wqkvT + 1024 * 1024,   1024, 1024);
    transpose_cvt<<<dim3(32, 32), 256, 0, stream>>>(Wv, wqkvT + 2 * 1024 * 1024, 1024, 1024);
    transpose_cvt<<<dim3(32, 32), 256, 0, stream>>>(Wo, woT,                   1024, 1024);
    transpose_cvt<<<dim3(128, 32), 256, 0, stream>>>(W1, w1T, 1024, 4096);
    transpose_cvt<<<dim3(32, 128), 256, 0, stream>>>(W2, w2T, 4096, 1024);
    concat_bias<<<12, 256, 0, stream>>>(bq, bk, bv, bqkv);

    // 2) LN1
    ln_kernel<<<NTOK, 256, 0, stream>>>(x, ln1g, ln1b, hbuf);

    // 3) QKV projection (fused): [8192,3072]
    gemm_bf16<0><<<dim3(3072 / 128, NTOK / 128), 256, 0, stream>>>(
        hbuf, wqkvT, bqkv, nullptr, qkv, NTOK, 3072, 1024);

    // 4a) V transpose to [bh][d][s]
    vtr_kernel<<<dim3(SEQ / 64, NBATCH * NHEAD), 256, 0, stream>>>(qkv, vTbuf);

    // 4b) attention
    attn_kernel<<<dim3(SEQ / 128, NBATCH * NHEAD), 256, 0, stream>>>(qkv, vTbuf, obuf);

    // 5) Wo projection + residual -> x2 (f32)
    gemm_bf16<1><<<dim3(1024 / 128, NTOK / 128), 256, 0, stream>>>(
        obuf, woT, bo, x, x2, NTOK, 1024, 1024);

    // 6) LN2
    ln_kernel<<<NTOK, 256, 0, stream>>>(x2, ln2g, ln2b, h2);

    // 7) W1 + exact GELU
    gemm_bf16<2><<<dim3(4096 / 128, NTOK / 128), 256, 0, stream>>>(
        h2, w1T, b1, nullptr, gbuf, NTOK, 4096, 1024);

    // 8) W2 + residual -> out (f32)
    gemm_bf16<3><<<dim3(1024 / 128, NTOK / 128), 256, 0, stream>>>(
        gbuf, w2T, b2, x2, d_out, NTOK, 1024, 4096);

    (void)in_sizes; (void)n_in; (void)out_size; (void)ws_size;
}

// Round 5
// 631.878 us; speedup vs baseline: 1.3756x; 1.2536x over previous
//
#include <hip/hip_runtime.h>
#include <hip/hip_bf16.h>
#include <math.h>

#define DM   1024
#define DFF  4096
#define NHEAD 16
#define DKH  64
#define SEQ  2048
#define NBATCH 4
#define NTOK 8192          // NBATCH*SEQ

typedef __attribute__((ext_vector_type(8))) __bf16 bf16x8;
typedef __attribute__((ext_vector_type(8))) short short8;
typedef __attribute__((ext_vector_type(4))) float f32x4;
typedef __attribute__((ext_vector_type(16))) float f32x16;
typedef __attribute__((ext_vector_type(4))) unsigned int u32x4;
typedef __attribute__((ext_vector_type(4))) unsigned short ushort4v;

__device__ __forceinline__ unsigned short f2bf(float f) {
    unsigned u = __builtin_bit_cast(unsigned, f);
    u += 0x7fffu + ((u >> 16) & 1u);   // round-to-nearest-even
    return (unsigned short)(u >> 16);
}

__device__ __forceinline__ void gload_lds16(const void* g, void* l) {
    __builtin_amdgcn_global_load_lds(
        (const __attribute__((address_space(1))) unsigned int*)g,
        (__attribute__((address_space(3))) unsigned int*)l, 16, 0, 0);
}

// ---------------- weight transpose + fp32->bf16 : dst[C][R] = src[R][C] ----------------
__global__ __launch_bounds__(256) void transpose_cvt(
        const float* __restrict__ src, unsigned short* __restrict__ dst, int R, int C) {
    __shared__ unsigned short tile[32][33];
    const int c0 = blockIdx.x * 32, r0 = blockIdx.y * 32;
    const int tx = threadIdx.x & 31, ty = threadIdx.x >> 5;   // ty 0..7
    #pragma unroll
    for (int j = 0; j < 32; j += 8)
        tile[ty + j][tx] = f2bf(src[(size_t)(r0 + ty + j) * C + (c0 + tx)]);
    __syncthreads();
    #pragma unroll
    for (int j = 0; j < 32; j += 8)
        dst[(size_t)(c0 + ty + j) * R + (r0 + tx)] = tile[tx][ty + j];
}

// ---------------- bias concat (bq|bk|bv) ----------------
__global__ __launch_bounds__(256) void concat_bias(
        const float* __restrict__ a, const float* __restrict__ b,
        const float* __restrict__ c, float* __restrict__ out) {
    int i = blockIdx.x * 256 + threadIdx.x;            // 0..3071
    out[i] = (i < 1024) ? a[i] : (i < 2048 ? b[i - 1024] : c[i - 2048]);
}

// ---------------- layernorm fp32 -> bf16 (one row per block) ----------------
__global__ __launch_bounds__(256) void ln_kernel(
        const float* __restrict__ x, const float* __restrict__ g,
        const float* __restrict__ b, unsigned short* __restrict__ out) {
    const int row = blockIdx.x, t = threadIdx.x;
    const float4 v = ((const float4*)(x + (size_t)row * DM))[t];
    float s1 = v.x + v.y + v.z + v.w;
    float s2 = v.x * v.x + v.y * v.y + v.z * v.z + v.w * v.w;
    #pragma unroll
    for (int off = 32; off > 0; off >>= 1) {
        s1 += __shfl_xor(s1, off, 64);
        s2 += __shfl_xor(s2, off, 64);
    }
    __shared__ float w1[4], w2[4];
    const int wid = t >> 6, lane = t & 63;
    if (lane == 0) { w1[wid] = s1; w2[wid] = s2; }
    __syncthreads();
    s1 = w1[0] + w1[1] + w1[2] + w1[3];
    s2 = w2[0] + w2[1] + w2[2] + w2[3];
    const float mu = s1 * (1.0f / DM);
    const float rs = rsqrtf(s2 * (1.0f / DM) - mu * mu + 1e-5f);
    const float4 gv = ((const float4*)g)[t];
    const float4 bv = ((const float4*)b)[t];
    ushort4v o;
    o[0] = f2bf((v.x - mu) * rs * gv.x + bv.x);
    o[1] = f2bf((v.y - mu) * rs * gv.y + bv.y);
    o[2] = f2bf((v.z - mu) * rs * gv.z + bv.z);
    o[3] = f2bf((v.w - mu) * rs * gv.w + bv.w);
    *(ushort4v*)(out + (size_t)row * DM + t * 4) = o;
}

// ---------------- bf16 GEMM: C[M,N] = A[M,K] * BT[N,K]^T + bias (+res) ----------------
// EP: 0 bias->bf16 | 1 bias+res->f32 | 2 bias+GELU->bf16 | 3 bias+res->f32
// EP: 4 bias-> packed qP/kP [bh][s][64] + tiled vT [bh][kvblk][d][32] (QKV projection)
template<int EP>
__global__ __launch_bounds__(256) void gemm_bf16(
        const unsigned short* __restrict__ A, const unsigned short* __restrict__ BT,
        const float* __restrict__ bias, const float* __restrict__ res,
        void* __restrict__ outp, int M, int N, int K) {
    const int lane = threadIdx.x & 63;
    const int wid  = threadIdx.x >> 6;
    const int m0 = blockIdx.y * 128;
    const int n0 = blockIdx.x * 128;
    __shared__ short As[128 * 32];
    __shared__ short Bs[128 * 32];
    f32x4 acc[4][4] = {};
    const int wm = wid >> 1, wn = wid & 1;
    const int srow = lane >> 2;          // 0..15
    const int scol = (lane & 3) << 3;    // 0,8,16,24

    for (int k0 = 0; k0 < K; k0 += 32) {
        __syncthreads();
        #pragma unroll
        for (int i = 0; i < 2; ++i) {
            const int rt = (wid * 2 + i) * 16;
            gload_lds16(A  + (size_t)(m0 + rt + srow) * K + k0 + scol, &As[(wid * 2 + i) * 512]);
            gload_lds16(BT + (size_t)(n0 + rt + srow) * K + k0 + scol, &Bs[(wid * 2 + i) * 512]);
        }
        __syncthreads();
        bf16x8 af[4], bfr[4];
        #pragma unroll
        for (int mi = 0; mi < 4; ++mi)
            af[mi] = *(const bf16x8*)&As[(wm * 64 + mi * 16 + (lane & 15)) * 32 + ((lane >> 4) << 3)];
        #pragma unroll
        for (int ni = 0; ni < 4; ++ni)
            bfr[ni] = *(const bf16x8*)&Bs[(wn * 64 + ni * 16 + (lane & 15)) * 32 + ((lane >> 4) << 3)];
        #pragma unroll
        for (int mi = 0; mi < 4; ++mi)
            #pragma unroll
            for (int ni = 0; ni < 4; ++ni)
                acc[mi][ni] = __builtin_amdgcn_mfma_f32_16x16x32_bf16(af[mi], bfr[ni], acc[mi][ni], 0, 0, 0);
    }

    const int r_base = m0 + wm * 64 + ((lane >> 4) << 2);
    const int c_base = n0 + wn * 64 + (lane & 15);

    if (EP == 4) {
        // QKV pack epilogue. col: [0,1024)=q, [1024,2048)=k, [2048,3072)=v
        unsigned short* qP = (unsigned short*)outp;
        unsigned short* kP = qP + (size_t)NTOK * 1024;
        unsigned short* vP = qP + (size_t)2 * NTOK * 1024;
        const int b  = m0 >> 11;                       // batch (2048-row chunks)
        const int sb = (m0 & 2047) + wm * 64 + ((lane >> 4) << 2);
        #pragma unroll
        for (int ni = 0; ni < 4; ++ni) {
            const int col = c_base + ni * 16;
            const int which = col >> 10;
            const int h = (col >> 6) & 15;
            const int d = col & 63;
            const float bv = bias[col];
            const size_t bh = (size_t)(b * NHEAD + h);
            if (which < 2) {
                unsigned short* dst = (which ? kP : qP) + bh * SEQ * 64 + d;
                #pragma unroll
                for (int mi = 0; mi < 4; ++mi)
                    #pragma unroll
                    for (int i = 0; i < 4; ++i)
                        dst[(size_t)(sb + mi * 16 + i) * 64] = f2bf(acc[mi][ni][i] + bv);
            } else {
                unsigned short* dst = vP + bh * SEQ * 64;
                #pragma unroll
                for (int mi = 0; mi < 4; ++mi) {
                    const int s0 = sb + mi * 16;
                    ushort4v o;
                    #pragma unroll
                    for (int i = 0; i < 4; ++i) o[i] = f2bf(acc[mi][ni][i] + bv);
                    *(ushort4v*)(dst + (s0 >> 5) * 2048 + d * 32 + (s0 & 31)) = o;
                }
            }
        }
        return;
    }

    #pragma unroll
    for (int ni = 0; ni < 4; ++ni) {
        const int col = c_base + ni * 16;
        const float bv = bias[col];
        #pragma unroll
        for (int mi = 0; mi < 4; ++mi) {
            #pragma unroll
            for (int i = 0; i < 4; ++i) {
                const int row = r_base + mi * 16 + i;
                const size_t idx = (size_t)row * N + col;
                float v = acc[mi][ni][i] + bv;
                if (EP == 1 || EP == 3) v += res[idx];
                if (EP == 2) v = 0.5f * v * (1.0f + erff(v * 0.70710678118f));
                if (EP == 0 || EP == 2) ((unsigned short*)outp)[idx] = f2bf(v);
                else                    ((float*)outp)[idx] = v;
            }
        }
    }
}

// ---------------- flash attention, swapped-QK^T 32x32, LDS-staged K/V ----------------
// qP/kP: [bh][s][64]; vP: [bh][kvblk][64 d][32 s]; o: [NTOK][1024]
__global__ __launch_bounds__(256, 4) void attn_kernel(
        const unsigned short* __restrict__ qP, const unsigned short* __restrict__ kP,
        const unsigned short* __restrict__ vP, unsigned short* __restrict__ o) {
    const int lane = threadIdx.x & 63;
    const int wid  = threadIdx.x >> 6;
    const int l31  = lane & 31;
    const int hi   = lane >> 5;
    const int bh = blockIdx.y;
    const int b = bh >> 4, h = bh & 15;
    const int q0 = blockIdx.x * 128 + wid * 32;   // this wave's 32 q rows

    __shared__ short Ks[2][2048];   // [32 row][8 chunk16] src-swizzled: chunk_src = c ^ (row&7)
    __shared__ short Vs[2][2048];   // [64 d][4 chunk16]  src-swizzled: chunk_src = c ^ ((d>>1)&3)
    __shared__ float lsum[4][32];

    // Q fragments (B-operand, col = q = l31, k = d-slice)
    bf16x8 qf[4];
    {
        const unsigned short* qp = qP + ((size_t)bh * SEQ + q0 + l31) * 64 + hi * 8;
        #pragma unroll
        for (int s = 0; s < 4; ++s) qf[s] = *(const bf16x8*)(qp + 16 * s);
    }

    // staging source offsets (elements), pre-swizzled so LDS dest stays linear
    const int krow  = wid * 8 + (lane >> 3);
    const int k_src = krow * 64 + (((lane & 7) ^ (lane >> 3)) << 3);
    const int vrow  = wid * 16 + (lane >> 2);
    const int v_src = vrow * 32 + (((lane & 3) ^ ((vrow >> 1) & 3)) << 3);
    const unsigned short* kb = kP + (size_t)bh * SEQ * 64 + k_src;
    const unsigned short* vb = vP + (size_t)bh * SEQ * 64 + v_src;
    short* ksd = &Ks[0][0] + wid * 512;   // wave-uniform LDS dest base
    short* vsd = &Vs[0][0] + wid * 512;

    auto STAGE = [&](int buf, int kv0) {
        gload_lds16(kb + (size_t)kv0 * 64, ksd + buf * 2048);
        gload_lds16(vb + (size_t)(kv0 >> 5) * 2048, vsd + buf * 2048);
    };

    STAGE(0, 0);
    asm volatile("s_waitcnt vmcnt(0)" ::: "memory");
    __builtin_amdgcn_s_barrier();

    f32x16 oacc0 = {}, oacc1 = {};
    float m_r = -1e30f, l_r = 0.0f;
    const float CE = 0.18033688011f;   // (1/8) * log2(e)

    for (int kv0 = 0; kv0 < SEQ; kv0 += 32) {
        const int cur = (kv0 >> 5) & 1;
        if (kv0 + 32 < SEQ) STAGE(cur ^ 1, kv0 + 32);

        const short* kc = &Ks[cur][0];
        const short* vc = &Vs[cur][0];
        // fragments from LDS (swizzled read)
        bf16x8 kf[4], vf[2][2];
        #pragma unroll
        for (int s = 0; s < 4; ++s)
            kf[s] = *(const bf16x8*)(kc + l31 * 64 + (((2 * s + hi) ^ (l31 & 7)) << 3));
        #pragma unroll
        for (int s = 0; s < 2; ++s)
            #pragma unroll
            for (int n = 0; n < 2; ++n) {
                const int d = l31 + 32 * n;
                vf[s][n] = *(const bf16x8*)(vc + d * 32 + (((2 * s + hi) ^ ((d >> 1) & 3)) << 3));
            }

        // QK^T: S^T[kv][q] = K * Q^T
        f32x16 S = {};
        #pragma unroll
        for (int s = 0; s < 4; ++s)
            S = __builtin_amdgcn_mfma_f32_32x32x16_bf16(kf[s], qf[s], S, 0, 0, 0);

        // online softmax: lane holds 16 kv-rows for one q (col = l31); tree reductions
        float t8[8];
        #pragma unroll
        for (int j = 0; j < 8; ++j) t8[j] = fmaxf(S[j], S[j + 8]);
        float tm = fmaxf(fmaxf(fmaxf(t8[0], t8[4]), fmaxf(t8[1], t8[5])),
                         fmaxf(fmaxf(t8[2], t8[6]), fmaxf(t8[3], t8[7])));
        tm = fmaxf(tm, __shfl_xor(tm, 32, 64));
        if (!__all(tm - m_r <= 44.0f)) {        // defer-max (T13): exp2 arg stays < 8
            const float mn = fmaxf(m_r, tm);
            const float es = exp2f((m_r - mn) * CE);
            l_r *= es;
            #pragma unroll
            for (int r = 0; r < 16; ++r) { oacc0[r] *= es; oacc1[r] *= es; }
            m_r = mn;
        }
        float p[16];
        #pragma unroll
        for (int r = 0; r < 16; ++r) p[r] = exp2f((S[r] - m_r) * CE);
        float a8[8];
        #pragma unroll
        for (int j = 0; j < 8; ++j) a8[j] = p[j] + p[j + 8];
        float rs = ((a8[0] + a8[4]) + (a8[1] + a8[5])) + ((a8[2] + a8[6]) + (a8[3] + a8[7]));
        rs += __shfl_xor(rs, 32, 64);
        l_r += rs;

        // P -> bf16 A-fragments via cvt_pk + permlane32_swap (T12)
        unsigned pk[8];
        #pragma unroll
        for (int i = 0; i < 8; ++i) {
            unsigned rr;
            asm("v_cvt_pk_bf16_f32 %0, %1, %2" : "=v"(rr) : "v"(p[2 * i]), "v"(p[2 * i + 1]));
            pk[i] = rr;
        }
        asm volatile("v_permlane32_swap_b32 %0, %1" : "+v"(pk[0]), "+v"(pk[2]));
        asm volatile("v_permlane32_swap_b32 %0, %1" : "+v"(pk[1]), "+v"(pk[3]));
        asm volatile("v_permlane32_swap_b32 %0, %1" : "+v"(pk[4]), "+v"(pk[6]));
        asm volatile("v_permlane32_swap_b32 %0, %1" : "+v"(pk[5]), "+v"(pk[7]));
        const bf16x8 A0 = __builtin_bit_cast(bf16x8, (u32x4){pk[0], pk[1], pk[2], pk[3]});
        const bf16x8 A1 = __builtin_bit_cast(bf16x8, (u32x4){pk[4], pk[5], pk[6], pk[7]});

        oacc0 = __builtin_amdgcn_mfma_f32_32x32x16_bf16(A0, vf[0][0], oacc0, 0, 0, 0);
        oacc1 = __builtin_amdgcn_mfma_f32_32x32x16_bf16(A0, vf[0][1], oacc1, 0, 0, 0);
        oacc0 = __builtin_amdgcn_mfma_f32_32x32x16_bf16(A1, vf[1][0], oacc0, 0, 0, 0);
        oacc1 = __builtin_amdgcn_mfma_f32_32x32x16_bf16(A1, vf[1][1], oacc1, 0, 0, 0);

        asm volatile("s_waitcnt vmcnt(0)" ::: "memory");
        __builtin_amdgcn_s_barrier();
    }

    // redistribute 1/l across lanes (O rows != S^T cols) via tiny per-wave LDS
    if (lane < 32) lsum[wid][l31] = 1.0f / l_r;
    float inv[16];
    #pragma unroll
    for (int r = 0; r < 16; ++r)
        inv[r] = lsum[wid][(r & 3) + 8 * (r >> 2) + 4 * hi];

    unsigned short* op = o + (size_t)(b * SEQ + q0) * DM + h * 64 + l31;
    #pragma unroll
    for (int r = 0; r < 16; ++r) {
        const int q = (r & 3) + 8 * (r >> 2) + 4 * hi;
        op[(size_t)q * DM]      = f2bf(oacc0[r] * inv[r]);
        op[(size_t)q * DM + 32] = f2bf(oacc1[r] * inv[r]);
    }
}

extern "C" void kernel_launch(void* const* d_in, const int* in_sizes, int n_in,
                              void* d_out, int out_size, void* d_ws, size_t ws_size,
                              hipStream_t stream) {
    const float* x    = (const float*)d_in[0];
    const float* Wq   = (const float*)d_in[1];
    const float* bq   = (const float*)d_in[2];
    const float* Wk   = (const float*)d_in[3];
    const float* bk   = (const float*)d_in[4];
    const float* Wv   = (const float*)d_in[5];
    const float* bv   = (const float*)d_in[6];
    const float* Wo   = (const float*)d_in[7];
    const float* bo   = (const float*)d_in[8];
    const float* ln1g = (const float*)d_in[9];
    const float* ln1b = (const float*)d_in[10];
    const float* ln2g = (const float*)d_in[11];
    const float* ln2b = (const float*)d_in[12];
    const float* W1   = (const float*)d_in[13];
    const float* b1   = (const float*)d_in[14];
    const float* W2   = (const float*)d_in[15];
    const float* b2   = (const float*)d_in[16];

    char* ws = (char*)d_ws;
    size_t off = 0;
    auto alloc = [&](size_t bytes) {
        char* p = ws + off;
        off = (off + bytes + 255) & ~(size_t)255;
        return p;
    };
    unsigned short* wqkvT = (unsigned short*)alloc((size_t)3072 * 1024 * 2);
    unsigned short* woT   = (unsigned short*)alloc((size_t)1024 * 1024 * 2);
    unsigned short* w1T   = (unsigned short*)alloc((size_t)4096 * 1024 * 2);
    unsigned short* w2T   = (unsigned short*)alloc((size_t)1024 * 4096 * 2);
    float*          bqkv  = (float*)alloc((size_t)3072 * 4);
    unsigned short* hbuf  = (unsigned short*)alloc((size_t)NTOK * DM * 2);
    unsigned short* pack  = (unsigned short*)alloc((size_t)NTOK * 3072 * 2);  // qP|kP|vP
    unsigned short* obuf  = (unsigned short*)alloc((size_t)NTOK * DM * 2);
    float*          x2    = (float*)alloc((size_t)NTOK * DM * 4);
    unsigned short* h2    = (unsigned short*)alloc((size_t)NTOK * DM * 2);
    unsigned short* gbuf  = (unsigned short*)alloc((size_t)NTOK * DFF * 2);

    const unsigned short* qP = pack;
    const unsigned short* kP = pack + (size_t)NTOK * 1024;
    const unsigned short* vP = pack + (size_t)2 * NTOK * 1024;

    // 1) weight transposes (fp32 -> bf16, [N][K])
    transpose_cvt<<<dim3(32, 32), 256, 0, stream>>>(Wq, wqkvT,                 1024, 1024);
    transpose_cvt<<<dim3(32, 32), 256, 0, stream>>>(Wk, wqkvT + 1024 * 1024,   1024, 1024);
    transpose_cvt<<<dim3(32, 32), 256, 0, stream>>>(Wv, wqkvT + 2 * 1024 * 1024, 1024, 1024);
    transpose_cvt<<<dim3(32, 32), 256, 0, stream>>>(Wo, woT,                   1024, 1024);
    transpose_cvt<<<dim3(128, 32), 256, 0, stream>>>(W1, w1T, 1024, 4096);
    transpose_cvt<<<dim3(32, 128), 256, 0, stream>>>(W2, w2T, 4096, 1024);
    concat_bias<<<12, 256, 0, stream>>>(bq, bk, bv, bqkv);

    // 2) LN1
    ln_kernel<<<NTOK, 256, 0, stream>>>(x, ln1g, ln1b, hbuf);

    // 3) QKV projection, packed epilogue: [8192,3072] -> qP/kP/vP
    gemm_bf16<4><<<dim3(3072 / 128, NTOK / 128), 256, 0, stream>>>(
        hbuf, wqkvT, bqkv, nullptr, pack, NTOK, 3072, 1024);

    // 4) attention
    attn_kernel<<<dim3(SEQ / 128, NBATCH * NHEAD), 256, 0, stream>>>(qP, kP, vP, obuf);

    // 5) Wo projection + residual -> x2 (f32)
    gemm_bf16<1><<<dim3(1024 / 128, NTOK / 128), 256, 0, stream>>>(
        obuf, woT, bo, x, x2, NTOK, 1024, 1024);

    // 6) LN2
    ln_kernel<<<NTOK, 256, 0, stream>>>(x2, ln2g, ln2b, h2);

    // 7) W1 + exact GELU
    gemm_bf16<2><<<dim3(4096 / 128, NTOK / 128), 256, 0, stream>>>(
        h2, w1T, b1, nullptr, gbuf, NTOK, 4096, 1024);

    // 8) W2 + residual -> out (f32)
    gemm_bf16<3><<<dim3(1024 / 128, NTOK / 128), 256, 0, stream>>>(
        gbuf, w2T, b2, x2, d_out, NTOK, 1024, 4096);

    (void)in_sizes; (void)n_in; (void)out_size; (void)ws_size;
}

// Round 6
// 613.527 us; speedup vs baseline: 1.4167x; 1.0299x over previous
//
#include <hip/hip_runtime.h>
#include <hip/hip_bf16.h>
#include <math.h>

#define DM   1024
#define DFF  4096
#define NHEAD 16
#define DKH  64
#define SEQ  2048
#define NBATCH 4
#define NTOK 8192          // NBATCH*SEQ

typedef __attribute__((ext_vector_type(8))) __bf16 bf16x8;
typedef __attribute__((ext_vector_type(8))) short short8;
typedef __attribute__((ext_vector_type(4))) float f32x4;
typedef __attribute__((ext_vector_type(16))) float f32x16;
typedef __attribute__((ext_vector_type(4))) unsigned int u32x4;
typedef __attribute__((ext_vector_type(4))) unsigned short ushort4v;

__device__ __forceinline__ unsigned short f2bf(float f) {
    unsigned u = __builtin_bit_cast(unsigned, f);
    u += 0x7fffu + ((u >> 16) & 1u);   // round-to-nearest-even
    return (unsigned short)(u >> 16);
}

__device__ __forceinline__ void gload_lds16(const void* g, void* l) {
    __builtin_amdgcn_global_load_lds(
        (const __attribute__((address_space(1))) unsigned int*)g,
        (__attribute__((address_space(3))) unsigned int*)l, 16, 0, 0);
}

// ---------------- weight transpose + fp32->bf16 : dst[C][R] = src[R][C] ----------------
__global__ __launch_bounds__(256) void transpose_cvt(
        const float* __restrict__ src, unsigned short* __restrict__ dst, int R, int C) {
    __shared__ unsigned short tile[32][33];
    const int c0 = blockIdx.x * 32, r0 = blockIdx.y * 32;
    const int tx = threadIdx.x & 31, ty = threadIdx.x >> 5;   // ty 0..7
    #pragma unroll
    for (int j = 0; j < 32; j += 8)
        tile[ty + j][tx] = f2bf(src[(size_t)(r0 + ty + j) * C + (c0 + tx)]);
    __syncthreads();
    #pragma unroll
    for (int j = 0; j < 32; j += 8)
        dst[(size_t)(c0 + ty + j) * R + (r0 + tx)] = tile[tx][ty + j];
}

// ---------------- bias concat (bq|bk|bv) ----------------
__global__ __launch_bounds__(256) void concat_bias(
        const float* __restrict__ a, const float* __restrict__ b,
        const float* __restrict__ c, float* __restrict__ out) {
    int i = blockIdx.x * 256 + threadIdx.x;            // 0..3071
    out[i] = (i < 1024) ? a[i] : (i < 2048 ? b[i - 1024] : c[i - 2048]);
}

// ---------------- layernorm fp32 -> bf16 (one row per block) ----------------
__global__ __launch_bounds__(256) void ln_kernel(
        const float* __restrict__ x, const float* __restrict__ g,
        const float* __restrict__ b, unsigned short* __restrict__ out) {
    const int row = blockIdx.x, t = threadIdx.x;
    const float4 v = ((const float4*)(x + (size_t)row * DM))[t];
    float s1 = v.x + v.y + v.z + v.w;
    float s2 = v.x * v.x + v.y * v.y + v.z * v.z + v.w * v.w;
    #pragma unroll
    for (int off = 32; off > 0; off >>= 1) {
        s1 += __shfl_xor(s1, off, 64);
        s2 += __shfl_xor(s2, off, 64);
    }
    __shared__ float w1[4], w2[4];
    const int wid = t >> 6, lane = t & 63;
    if (lane == 0) { w1[wid] = s1; w2[wid] = s2; }
    __syncthreads();
    s1 = w1[0] + w1[1] + w1[2] + w1[3];
    s2 = w2[0] + w2[1] + w2[2] + w2[3];
    const float mu = s1 * (1.0f / DM);
    const float rs = rsqrtf(s2 * (1.0f / DM) - mu * mu + 1e-5f);
    const float4 gv = ((const float4*)g)[t];
    const float4 bv = ((const float4*)b)[t];
    ushort4v o;
    o[0] = f2bf((v.x - mu) * rs * gv.x + bv.x);
    o[1] = f2bf((v.y - mu) * rs * gv.y + bv.y);
    o[2] = f2bf((v.z - mu) * rs * gv.z + bv.z);
    o[3] = f2bf((v.w - mu) * rs * gv.w + bv.w);
    *(ushort4v*)(out + (size_t)row * DM + t * 4) = o;
}

// ======== 4-phase pipelined bf16 GEMM (T2 swizzle + T3/T4 counted vmcnt + T5) ========
// C[M,N] = A[M,K] * BT[N,K]^T + bias (+res). 512 thr = 8 waves (2M x 4N), BK=64.
// Reg-staged: global->reg (2 tiles deep) -> swizzled ds_write. 1 raw barrier/tile.
// EP: 0 bias->bf16 | 1 bias+res->f32 | 2 bias+GELU->bf16 | 3 bias+res->f32 | 4 QKV pack
#define LGKM0 do { asm volatile("s_waitcnt lgkmcnt(0)" ::: "memory"); \
                   __builtin_amdgcn_sched_barrier(0); } while (0)
#define SB0   __builtin_amdgcn_sched_barrier(0)

template<int BM, int BN, int EP>
__global__ __launch_bounds__(512, 2) void gemm8p(
        const unsigned short* __restrict__ A, const unsigned short* __restrict__ BT,
        const float* __restrict__ bias, const float* __restrict__ res,
        void* __restrict__ outp, int M, int N, int K) {
    constexpr int WM = BM / 2, WN = BN / 4;    // per-wave output span
    constexpr int MR = WM / 16, NR = WN / 16;  // fragment repeats (MR 8|4, NR 4)
    constexpr int MH = MR / 2;                 // M-frags per phase
    constexpr int LA = BM / 64, LB = BN / 64;  // stage loads/thread (A, B)

    const int t = threadIdx.x;
    const int lane = t & 63, wid = t >> 6;
    const int wr = wid >> 2, wc = wid & 3;
    const int m0 = blockIdx.y * BM, n0 = blockIdx.x * BN;
    const int NT = K >> 6;

    __shared__ alignas(16) short As[2 * BM * 64];
    __shared__ alignas(16) short Bs[2 * BN * 64];

    // ---- staging addressing: thread covers row (t>>3), 16B chunk (t&7) ----
    const int srow = t >> 3, schk = t & 7;
    const int sw = ((schk ^ (srow & 7)) << 3);           // swizzled chunk offset
    const unsigned short* gA = A  + (size_t)(m0 + srow) * K + (schk << 3);
    const unsigned short* gB = BT + (size_t)(n0 + srow) * K + (schk << 3);

    bf16x8 rA[LA], rB[LB];
    bf16x8 fa[MH][2], fb[4][2];
    f32x4 acc[MR][NR] = {};

    auto LOADA = [&](int tile) {
        const unsigned short* p = gA + tile * 64;
        #pragma unroll
        for (int j = 0; j < LA; ++j) rA[j] = *(const bf16x8*)(p + (size_t)j * 64 * K);
    };
    auto LOADB = [&](int tile) {
        const unsigned short* p = gB + tile * 64;
        #pragma unroll
        for (int j = 0; j < LB; ++j) rB[j] = *(const bf16x8*)(p + (size_t)j * 64 * K);
    };
    auto WRA = [&](int q) {
        short* d = As + q * (BM * 64) + srow * 64 + sw;
        #pragma unroll
        for (int j = 0; j < LA; ++j) *(bf16x8*)(d + j * 4096) = rA[j];
    };
    auto WRB = [&](int q) {
        short* d = Bs + q * (BN * 64) + srow * 64 + sw;
        #pragma unroll
        for (int j = 0; j < LB; ++j) *(bf16x8*)(d + j * 4096) = rB[j];
    };
    auto RDA = [&](int p, int mh) {
        const short* base = As + p * (BM * 64);
        #pragma unroll
        for (int m = 0; m < MH; ++m) {
            const int row = wr * WM + (mh * MH + m) * 16 + (lane & 15);
            #pragma unroll
            for (int kk = 0; kk < 2; ++kk)
                fa[m][kk] = *(const bf16x8*)(base + row * 64 +
                    ((((kk << 2) | (lane >> 4)) ^ (lane & 7)) << 3));
        }
    };
    auto RDB = [&](int p, int nh) {
        const short* base = Bs + p * (BN * 64);
        #pragma unroll
        for (int n = 0; n < 2; ++n) {
            const int row = wc * WN + (nh * 2 + n) * 16 + (lane & 15);
            #pragma unroll
            for (int kk = 0; kk < 2; ++kk)
                fb[nh * 2 + n][kk] = *(const bf16x8*)(base + row * 64 +
                    ((((kk << 2) | (lane >> 4)) ^ (lane & 7)) << 3));
        }
    };

#define MMA(mh, nh)                                                            \
    do {                                                                       \
        _Pragma("unroll")                                                      \
        for (int m_ = 0; m_ < MH; ++m_)                                        \
            _Pragma("unroll")                                                  \
            for (int n_ = 0; n_ < 2; ++n_)                                     \
                _Pragma("unroll")                                              \
                for (int kk_ = 0; kk_ < 2; ++kk_)                              \
                    acc[(mh) * MH + m_][(nh) * 2 + n_] =                       \
                        __builtin_amdgcn_mfma_f32_16x16x32_bf16(               \
                            fa[m_][kk_], fb[(nh) * 2 + n_][kk_],               \
                            acc[(mh) * MH + m_][(nh) * 2 + n_], 0, 0, 0);      \
    } while (0)

    // ---- prologue: tile0 -> LDS(buf0); tile1 loads in flight ----
    LOADA(0); SB0; LOADB(0);
    asm volatile("s_waitcnt vmcnt(0)" ::: "memory");
    WRA(0); WRB(0);
    LOADA(NT > 1 ? 1 : 0); SB0; LOADB(NT > 1 ? 1 : 0);
    asm volatile("s_waitcnt lgkmcnt(0)" ::: "memory");
    SB0;
    __builtin_amdgcn_s_barrier();
    asm volatile("" ::: "memory");

    for (int tt = 0; tt < NT; ++tt) {
        const int p = tt & 1, q = p ^ 1;
        const int tp2 = (tt + 2 < NT) ? tt + 2 : NT - 1;
        // ---- P0: frags (mh0, nh0) ----
        RDA(p, 0); RDB(p, 0);
        LGKM0;
        __builtin_amdgcn_s_setprio(1); MMA(0, 0); __builtin_amdgcn_s_setprio(0);
        // ---- P1: frags nh1; land+write A(t+1); issue A(t+2) ----
        RDB(p, 1);
        asm volatile("s_waitcnt vmcnt(4)" ::: "memory");
        WRA(q);
        LGKM0;
        LOADA(tp2);
        SB0;
        __builtin_amdgcn_s_setprio(1); MMA(0, 1); __builtin_amdgcn_s_setprio(0);
        // ---- P2: frags mh1; land+write B(t+1); issue B(t+2) ----
        RDA(p, 1);
        if constexpr (LA == 4) { asm volatile("s_waitcnt vmcnt(4)" ::: "memory"); }
        else                   { asm volatile("s_waitcnt vmcnt(2)" ::: "memory"); }
        WRB(q);
        LGKM0;
        LOADB(tp2);
        SB0;
        __builtin_amdgcn_s_setprio(1); MMA(1, 1); __builtin_amdgcn_s_setprio(0);
        // ---- P3: remaining quadrant; end-of-tile barrier ----
        __builtin_amdgcn_s_setprio(1); MMA(1, 0); __builtin_amdgcn_s_setprio(0);
        __builtin_amdgcn_s_barrier();
        asm volatile("" ::: "memory");
    }
#undef MMA

    // ---- epilogue ----
    const int r_base = m0 + wr * WM + ((lane >> 4) << 2);
    const int c_base = n0 + wc * WN + (lane & 15);

    if constexpr (EP == 4) {
        // QKV pack. col: [0,1024)=q, [1024,2048)=k, [2048,3072)=v
        unsigned short* qP = (unsigned short*)outp;
        unsigned short* kP = qP + (size_t)NTOK * 1024;
        unsigned short* vP = qP + (size_t)2 * NTOK * 1024;
        const int b  = m0 >> 11;
        const int sb = (m0 & 2047) + wr * WM + ((lane >> 4) << 2);
        #pragma unroll
        for (int ni = 0; ni < NR; ++ni) {
            const int col = c_base + ni * 16;
            const int which = col >> 10;
            const int h = (col >> 6) & 15;
            const int d = col & 63;
            const float bv = bias[col];
            const size_t bh = (size_t)(b * NHEAD + h);
            if (which < 2) {
                unsigned short* dst = (which ? kP : qP) + bh * SEQ * 64 + d;
                #pragma unroll
                for (int mi = 0; mi < MR; ++mi)
                    #pragma unroll
                    for (int i = 0; i < 4; ++i)
                        dst[(size_t)(sb + mi * 16 + i) * 64] = f2bf(acc[mi][ni][i] + bv);
            } else {
                unsigned short* dst = vP + bh * SEQ * 64;
                #pragma unroll
                for (int mi = 0; mi < MR; ++mi) {
                    const int s0 = sb + mi * 16;
                    ushort4v o;
                    #pragma unroll
                    for (int i = 0; i < 4; ++i) o[i] = f2bf(acc[mi][ni][i] + bv);
                    *(ushort4v*)(dst + (s0 >> 5) * 2048 + d * 32 + (s0 & 31)) = o;
                }
            }
        }
        return;
    }

    #pragma unroll
    for (int ni = 0; ni < NR; ++ni) {
        const int col = c_base + ni * 16;
        const float bv = bias[col];
        #pragma unroll
        for (int mi = 0; mi < MR; ++mi) {
            #pragma unroll
            for (int i = 0; i < 4; ++i) {
                const int row = r_base + mi * 16 + i;
                const size_t idx = (size_t)row * N + col;
                float v = acc[mi][ni][i] + bv;
                if (EP == 1 || EP == 3) v += res[idx];
                if (EP == 2) v = 0.5f * v * (1.0f + erff(v * 0.70710678118f));
                if (EP == 0 || EP == 2) ((unsigned short*)outp)[idx] = f2bf(v);
                else                    ((float*)outp)[idx] = v;
            }
        }
    }
}

// ---------------- flash attention, swapped-QK^T 32x32, LDS-staged K/V ----------------
// qP/kP: [bh][s][64]; vP: [bh][kvblk][64 d][32 s]; o: [NTOK][1024]
__global__ __launch_bounds__(256, 4) void attn_kernel(
        const unsigned short* __restrict__ qP, const unsigned short* __restrict__ kP,
        const unsigned short* __restrict__ vP, unsigned short* __restrict__ o) {
    const int lane = threadIdx.x & 63;
    const int wid  = threadIdx.x >> 6;
    const int l31  = lane & 31;
    const int hi   = lane >> 5;
    const int bh = blockIdx.y;
    const int b = bh >> 4, h = bh & 15;
    const int q0 = blockIdx.x * 128 + wid * 32;   // this wave's 32 q rows

    __shared__ short Ks[2][2048];   // [32 row][8 chunk16] src-swizzled: chunk_src = c ^ (row&7)
    __shared__ short Vs[2][2048];   // [64 d][4 chunk16]  src-swizzled: chunk_src = c ^ ((d>>1)&3)
    __shared__ float lsum[4][32];

    // Q fragments (B-operand, col = q = l31, k = d-slice)
    bf16x8 qf[4];
    {
        const unsigned short* qp = qP + ((size_t)bh * SEQ + q0 + l31) * 64 + hi * 8;
        #pragma unroll
        for (int s = 0; s < 4; ++s) qf[s] = *(const bf16x8*)(qp + 16 * s);
    }

    // staging source offsets (elements), pre-swizzled so LDS dest stays linear
    const int krow  = wid * 8 + (lane >> 3);
    const int k_src = krow * 64 + (((lane & 7) ^ (lane >> 3)) << 3);
    const int vrow  = wid * 16 + (lane >> 2);
    const int v_src = vrow * 32 + (((lane & 3) ^ ((vrow >> 1) & 3)) << 3);
    const unsigned short* kb = kP + (size_t)bh * SEQ * 64 + k_src;
    const unsigned short* vb = vP + (size_t)bh * SEQ * 64 + v_src;
    short* ksd = &Ks[0][0] + wid * 512;   // wave-uniform LDS dest base
    short* vsd = &Vs[0][0] + wid * 512;

    auto STAGE = [&](int buf, int kv0) {
        gload_lds16(kb + (size_t)kv0 * 64, ksd + buf * 2048);
        gload_lds16(vb + (size_t)(kv0 >> 5) * 2048, vsd + buf * 2048);
    };

    STAGE(0, 0);
    asm volatile("s_waitcnt vmcnt(0)" ::: "memory");
    __builtin_amdgcn_s_barrier();

    f32x16 oacc0 = {}, oacc1 = {};
    float m_r = -1e30f, l_r = 0.0f;
    const float CE = 0.18033688011f;   // (1/8) * log2(e)

    for (int kv0 = 0; kv0 < SEQ; kv0 += 32) {
        const int cur = (kv0 >> 5) & 1;
        if (kv0 + 32 < SEQ) STAGE(cur ^ 1, kv0 + 32);

        const short* kc = &Ks[cur][0];
        const short* vc = &Vs[cur][0];
        // fragments from LDS (swizzled read)
        bf16x8 kf[4], vf[2][2];
        #pragma unroll
        for (int s = 0; s < 4; ++s)
            kf[s] = *(const bf16x8*)(kc + l31 * 64 + (((2 * s + hi) ^ (l31 & 7)) << 3));
        #pragma unroll
        for (int s = 0; s < 2; ++s)
            #pragma unroll
            for (int n = 0; n < 2; ++n) {
                const int d = l31 + 32 * n;
                vf[s][n] = *(const bf16x8*)(vc + d * 32 + (((2 * s + hi) ^ ((d >> 1) & 3)) << 3));
            }

        // QK^T: S^T[kv][q] = K * Q^T
        f32x16 S = {};
        #pragma unroll
        for (int s = 0; s < 4; ++s)
            S = __builtin_amdgcn_mfma_f32_32x32x16_bf16(kf[s], qf[s], S, 0, 0, 0);

        // online softmax: lane holds 16 kv-rows for one q (col = l31); tree reductions
        float t8[8];
        #pragma unroll
        for (int j = 0; j < 8; ++j) t8[j] = fmaxf(S[j], S[j + 8]);
        float tm = fmaxf(fmaxf(fmaxf(t8[0], t8[4]), fmaxf(t8[1], t8[5])),
                         fmaxf(fmaxf(t8[2], t8[6]), fmaxf(t8[3], t8[7])));
        tm = fmaxf(tm, __shfl_xor(tm, 32, 64));
        if (!__all(tm - m_r <= 44.0f)) {        // defer-max (T13): exp2 arg stays < 8
            const float mn = fmaxf(m_r, tm);
            const float es = exp2f((m_r - mn) * CE);
            l_r *= es;
            #pragma unroll
            for (int r = 0; r < 16; ++r) { oacc0[r] *= es; oacc1[r] *= es; }
            m_r = mn;
        }
        float p[16];
        #pragma unroll
        for (int r = 0; r < 16; ++r) p[r] = exp2f((S[r] - m_r) * CE);
        float a8[8];
        #pragma unroll
        for (int j = 0; j < 8; ++j) a8[j] = p[j] + p[j + 8];
        float rs = ((a8[0] + a8[4]) + (a8[1] + a8[5])) + ((a8[2] + a8[6]) + (a8[3] + a8[7]));
        rs += __shfl_xor(rs, 32, 64);
        l_r += rs;

        // P -> bf16 A-fragments via cvt_pk + permlane32_swap (T12)
        unsigned pk[8];
        #pragma unroll
        for (int i = 0; i < 8; ++i) {
            unsigned rr;
            asm("v_cvt_pk_bf16_f32 %0, %1, %2" : "=v"(rr) : "v"(p[2 * i]), "v"(p[2 * i + 1]));
            pk[i] = rr;
        }
        asm volatile("v_permlane32_swap_b32 %0, %1" : "+v"(pk[0]), "+v"(pk[2]));
        asm volatile("v_permlane32_swap_b32 %0, %1" : "+v"(pk[1]), "+v"(pk[3]));
        asm volatile("v_permlane32_swap_b32 %0, %1" : "+v"(pk[4]), "+v"(pk[6]));
        asm volatile("v_permlane32_swap_b32 %0, %1" : "+v"(pk[5]), "+v"(pk[7]));
        const bf16x8 A0 = __builtin_bit_cast(bf16x8, (u32x4){pk[0], pk[1], pk[2], pk[3]});
        const bf16x8 A1 = __builtin_bit_cast(bf16x8, (u32x4){pk[4], pk[5], pk[6], pk[7]});

        oacc0 = __builtin_amdgcn_mfma_f32_32x32x16_bf16(A0, vf[0][0], oacc0, 0, 0, 0);
        oacc1 = __builtin_amdgcn_mfma_f32_32x32x16_bf16(A0, vf[0][1], oacc1, 0, 0, 0);
        oacc0 = __builtin_amdgcn_mfma_f32_32x32x16_bf16(A1, vf[1][0], oacc0, 0, 0, 0);
        oacc1 = __builtin_amdgcn_mfma_f32_32x32x16_bf16(A1, vf[1][1], oacc1, 0, 0, 0);

        asm volatile("s_waitcnt vmcnt(0)" ::: "memory");
        __builtin_amdgcn_s_barrier();
    }

    // redistribute 1/l across lanes (O rows != S^T cols) via tiny per-wave LDS
    if (lane < 32) lsum[wid][l31] = 1.0f / l_r;
    float inv[16];
    #pragma unroll
    for (int r = 0; r < 16; ++r)
        inv[r] = lsum[wid][(r & 3) + 8 * (r >> 2) + 4 * hi];

    unsigned short* op = o + (size_t)(b * SEQ + q0) * DM + h * 64 + l31;
    #pragma unroll
    for (int r = 0; r < 16; ++r) {
        const int q = (r & 3) + 8 * (r >> 2) + 4 * hi;
        op[(size_t)q * DM]      = f2bf(oacc0[r] * inv[r]);
        op[(size_t)q * DM + 32] = f2bf(oacc1[r] * inv[r]);
    }
}

extern "C" void kernel_launch(void* const* d_in, const int* in_sizes, int n_in,
                              void* d_out, int out_size, void* d_ws, size_t ws_size,
                              hipStream_t stream) {
    const float* x    = (const float*)d_in[0];
    const float* Wq   = (const float*)d_in[1];
    const float* bq   = (const float*)d_in[2];
    const float* Wk   = (const float*)d_in[3];
    const float* bk   = (const float*)d_in[4];
    const float* Wv   = (const float*)d_in[5];
    const float* bv   = (const float*)d_in[6];
    const float* Wo   = (const float*)d_in[7];
    const float* bo   = (const float*)d_in[8];
    const float* ln1g = (const float*)d_in[9];
    const float* ln1b = (const float*)d_in[10];
    const float* ln2g = (const float*)d_in[11];
    const float* ln2b = (const float*)d_in[12];
    const float* W1   = (const float*)d_in[13];
    const float* b1   = (const float*)d_in[14];
    const float* W2   = (const float*)d_in[15];
    const float* b2   = (const float*)d_in[16];

    char* ws = (char*)d_ws;
    size_t off = 0;
    auto alloc = [&](size_t bytes) {
        char* p = ws + off;
        off = (off + bytes + 255) & ~(size_t)255;
        return p;
    };
    unsigned short* wqkvT = (unsigned short*)alloc((size_t)3072 * 1024 * 2);
    unsigned short* woT   = (unsigned short*)alloc((size_t)1024 * 1024 * 2);
    unsigned short* w1T   = (unsigned short*)alloc((size_t)4096 * 1024 * 2);
    unsigned short* w2T   = (unsigned short*)alloc((size_t)1024 * 4096 * 2);
    float*          bqkv  = (float*)alloc((size_t)3072 * 4);
    unsigned short* hbuf  = (unsigned short*)alloc((size_t)NTOK * DM * 2);
    unsigned short* pack  = (unsigned short*)alloc((size_t)NTOK * 3072 * 2);  // qP|kP|vP
    unsigned short* obuf  = (unsigned short*)alloc((size_t)NTOK * DM * 2);
    float*          x2    = (float*)alloc((size_t)NTOK * DM * 4);
    unsigned short* h2    = (unsigned short*)alloc((size_t)NTOK * DM * 2);
    unsigned short* gbuf  = (unsigned short*)alloc((size_t)NTOK * DFF * 2);

    const unsigned short* qP = pack;
    const unsigned short* kP = pack + (size_t)NTOK * 1024;
    const unsigned short* vP = pack + (size_t)2 * NTOK * 1024;

    // 1) weight transposes (fp32 -> bf16, [N][K])
    transpose_cvt<<<dim3(32, 32), 256, 0, stream>>>(Wq, wqkvT,                 1024, 1024);
    transpose_cvt<<<dim3(32, 32), 256, 0, stream>>>(Wk, wqkvT + 1024 * 1024,   1024, 1024);
    transpose_cvt<<<dim3(32, 32), 256, 0, stream>>>(Wv, wqkvT + 2 * 1024 * 1024, 1024, 1024);
    transpose_cvt<<<dim3(32, 32), 256, 0, stream>>>(Wo, woT,                   1024, 1024);
    transpose_cvt<<<dim3(128, 32), 256, 0, stream>>>(W1, w1T, 1024, 4096);
    transpose_cvt<<<dim3(32, 128), 256, 0, stream>>>(W2, w2T, 4096, 1024);
    concat_bias<<<12, 256, 0, stream>>>(bq, bk, bv, bqkv);

    // 2) LN1
    ln_kernel<<<NTOK, 256, 0, stream>>>(x, ln1g, ln1b, hbuf);

    // 3) QKV projection, packed epilogue: [8192,3072] -> qP/kP/vP
    gemm8p<256, 256, 4><<<dim3(3072 / 256, NTOK / 256), 512, 0, stream>>>(
        hbuf, wqkvT, bqkv, nullptr, pack, NTOK, 3072, 1024);

    // 4) attention
    attn_kernel<<<dim3(SEQ / 128, NBATCH * NHEAD), 256, 0, stream>>>(qP, kP, vP, obuf);

    // 5) Wo projection + residual -> x2 (f32)
    gemm8p<128, 256, 1><<<dim3(1024 / 256, NTOK / 128), 512, 0, stream>>>(
        obuf, woT, bo, x, x2, NTOK, 1024, 1024);

    // 6) LN2
    ln_kernel<<<NTOK, 256, 0, stream>>>(x2, ln2g, ln2b, h2);

    // 7) W1 + exact GELU
    gemm8p<256, 256, 2><<<dim3(4096 / 256, NTOK / 256), 512, 0, stream>>>(
        h2, w1T, b1, nullptr, gbuf, NTOK, 4096, 1024);

    // 8) W2 + residual -> out (f32)
    gemm8p<128, 256, 3><<<dim3(1024 / 256, NTOK / 128), 512, 0, stream>>>(
        gbuf, w2T, b2, x2, d_out, NTOK, 1024, 4096);

    (void)in_sizes; (void)n_in; (void)out_size; (void)ws_size;
}